// Round 16
// baseline (138.586 us; speedup 1.0000x reference)
//
#include <hip/hip_runtime.h>

// ArcMarginLoss fused: normalize -> MX-fp4 MFMA GEMM + fixed-max softmax -> NLL mean.
// N=8192, D=512, C=32000, scale=16, margin=0.2.
// R16: A/B test on hidden VALU. R15 showed MfmaUtil 26% (fp4 floor reached) but
// VALUBusy stuck at 31% with ~110cyc/chunk unexplained -> suspect per-MFMA
// i32x4->i32x8 tuple construction (up8 inside every call). Fix: operands live as
// native i32x8 (low 4 = payload, built ONCE); refills write the low half in place
// so loads land directly in the tuple regs. setprio dropped (m190: GEMM-negative).

typedef __attribute__((ext_vector_type(4))) float f32x4;
typedef __attribute__((ext_vector_type(4))) int i32x4;
typedef __attribute__((ext_vector_type(8))) int i32x8;

constexpr int N = 8192, D = 512, C = 32000;
constexpr int BM = 128;            // rows per block (4 waves x 2 tiles x 16 rows)
constexpr int NSPLIT = 16;         // column splits of C
constexpr int CPS = C / NSPLIT;    // 2000 cols per split
constexpr int NCHUNK = CPS / 16;   // 125 chunks of 16 cols
constexpr int KS = 4;              // 4 k-steps of K=128
constexpr float SCL = 16.0f;
constexpr float LOG2E = 1.4426950408889634f;
constexpr float S2 = SCL * LOG2E;              // folded into A pre-quant
constexpr float COSM = 0.98006657784124163f;  // cos(0.2)
constexpr float SINM = 0.19866933079506122f;  // sin(0.2)
constexpr float EPSC = 1e-7f;
constexpr float EM16 = 1.12535174719259114e-07f;  // exp(-16)
constexpr float FEC = 1064871712.0f;  // Schraudolph zero-mean magic (validated R12)

// fp4 e2m1 magnitude grid {0,.5,1,1.5,2,3,4,6} at codes 0..7.
__device__ __forceinline__ unsigned enc_fp4(float v, float inv) {
  unsigned s = (__float_as_uint(v) >> 31) << 3;
  float m = fabsf(v) * inv;
  float r = m < 2.0f ? 2.0f * m : (m < 4.0f ? m + 2.0f : fmaf(m, 0.5f, 4.0f));
  unsigned q = (unsigned)(r + 0.5f);
  return s | (q > 7u ? 7u : q);
}

// Per-32-block E8M0 scale from block absmax: smallest 2^e with absmax/2^e <= 6.
__device__ __forceinline__ void block_scale(float amax, unsigned& eB, float& inv) {
  unsigned u = __float_as_uint(amax * (1.0f / 6.0f));
  eB = (u >> 23) & 255u;
  if (u & 0x7fffffu) eB += 1u;      // ceil
  if (eB < 1u) eB = 1u;
  if (eB > 254u) eB = 254u;
  inv = __uint_as_float((254u - eB) << 23);  // 2^(127-eB)
}

// x: one wave per row. v = x_hat * S2; per-32-block scale; emit fp4 nibbles
// (row stride 256B) + scale bytes [row][g][ks] (16B/row). Zero-inits out scalar.
__global__ void k_norm_x(const float* __restrict__ in, unsigned* __restrict__ xn4,
                         unsigned char* __restrict__ xsc, float* __restrict__ outz) {
  if (blockIdx.x == 0 && threadIdx.x == 0) *outz = 0.0f;
  int w = (blockIdx.x << 2) + (threadIdx.x >> 6);
  int L = threadIdx.x & 63;
  const float* row = in + (size_t)w * D;
  float f[8];
  *(f32x4*)&f[0] = *(const f32x4*)(row + L * 8);
  *(f32x4*)&f[4] = *(const f32x4*)(row + L * 8 + 4);
  float ss = 0.f;
  #pragma unroll
  for (int i = 0; i < 8; ++i) ss += f[i] * f[i];
  #pragma unroll
  for (int m = 1; m <= 32; m <<= 1) ss += __shfl_xor(ss, m, 64);
  float sc = S2 / fmaxf(sqrtf(ss), 1e-12f);
  float v[8], am = 0.f;
  #pragma unroll
  for (int i = 0; i < 8; ++i) { v[i] = f[i] * sc; am = fmaxf(am, fabsf(v[i])); }
  am = fmaxf(am, __shfl_xor(am, 1, 64));
  am = fmaxf(am, __shfl_xor(am, 2, 64));   // quad (= one 32-elem block) absmax
  unsigned eB; float inv;
  block_scale(am, eB, inv);
  unsigned pk = 0;
  #pragma unroll
  for (int j = 0; j < 8; ++j) pk |= enc_fp4(v[j], inv) << (4 * j);
  xn4[(size_t)w * 64 + L] = pk;
  if ((L & 3) == 0) {
    int kb = L >> 2;  // block index; stored at [row][g=kb&3][ks=kb>>2]
    xsc[(size_t)w * 16 + (kb & 3) * 4 + (kb >> 2)] = (unsigned char)eB;
  }
}

// w: one block per 16-col group. Quantize to fp4 with per-32-block scales; emit
// chunk image (4KB, lane-contiguous for the fused per-lane 16B read) + 256B
// scale image [col][g][ks].
__global__ void k_normw_t(const float* __restrict__ in, unsigned char* __restrict__ wt4,
                          unsigned char* __restrict__ wsc) {
  __shared__ unsigned lbuf[1024];         // 4KB chunk image
  __shared__ unsigned char sbuf[256];     // scale image
  const int tid = threadIdx.x, wv = tid >> 6, L = tid & 63;
  const int gidx = blockIdx.x;
  #pragma unroll
  for (int t = 0; t < 4; ++t) {
    int rl = t * 4 + wv;  // 0..15 (col within group)
    const float* row = in + ((size_t)gidx * 16 + rl) * D;
    float f[8];
    *(f32x4*)&f[0] = *(const f32x4*)(row + L * 8);
    *(f32x4*)&f[4] = *(const f32x4*)(row + L * 8 + 4);
    float ss = 0.f;
    #pragma unroll
    for (int i = 0; i < 8; ++i) ss += f[i] * f[i];
    #pragma unroll
    for (int m = 1; m <= 32; m <<= 1) ss += __shfl_xor(ss, m, 64);
    float sc = 1.0f / fmaxf(sqrtf(ss), 1e-12f);
    float v[8], am = 0.f;
    #pragma unroll
    for (int i = 0; i < 8; ++i) { v[i] = f[i] * sc; am = fmaxf(am, fabsf(v[i])); }
    am = fmaxf(am, __shfl_xor(am, 1, 64));
    am = fmaxf(am, __shfl_xor(am, 2, 64));
    unsigned eB; float inv;
    block_scale(am, eB, inv);
    unsigned pk = 0;
    #pragma unroll
    for (int j = 0; j < 8; ++j) pk |= enc_fp4(v[j], inv) << (4 * j);
    // lane L covers k=8L..8L+8: ks=L>>4, g=(L>>2)&3, dword slot (L&3)
    lbuf[(L >> 4) * 256 + (((L >> 2) & 3) * 16 + rl) * 4 + (L & 3)] = pk;
    if ((L & 3) == 0)
      sbuf[rl * 16 + ((L >> 2) & 3) * 4 + (L >> 4)] = (unsigned char)eB;
  }
  __syncthreads();
  uint4* dst = (uint4*)(wt4 + (size_t)gidx * 4096);
  dst[tid] = ((const uint4*)lbuf)[tid];
  if (tid < 64)
    ((unsigned*)(wsc + (size_t)gidx * 256))[tid] = ((const unsigned*)sbuf)[tid];
}

// Label-column cosine in f32 (one wave per row) -> coslab[N].
__global__ void k_lab(const float* __restrict__ x, const float* __restrict__ w,
                      const int* __restrict__ labels, float* __restrict__ coslab) {
  int r = (blockIdx.x << 2) + (threadIdx.x >> 6);
  int lane = threadIdx.x & 63;
  const float* xr = x + (size_t)r * D;
  const float* wr = w + (size_t)labels[r] * D;
  f32x4 a = *(const f32x4*)(xr + lane * 8);
  f32x4 b = *(const f32x4*)(xr + lane * 8 + 4);
  f32x4 p = *(const f32x4*)(wr + lane * 8);
  f32x4 q = *(const f32x4*)(wr + lane * 8 + 4);
  float xx = a.x*a.x + a.y*a.y + a.z*a.z + a.w*a.w + b.x*b.x + b.y*b.y + b.z*b.z + b.w*b.w;
  float ww = p.x*p.x + p.y*p.y + p.z*p.z + p.w*p.w + q.x*q.x + q.y*q.y + q.z*q.z + q.w*q.w;
  float xw = a.x*p.x + a.y*p.y + a.z*p.z + a.w*p.w + b.x*q.x + b.y*q.y + b.z*q.z + b.w*q.w;
  #pragma unroll
  for (int m = 1; m <= 32; m <<= 1) {
    xx += __shfl_xor(xx, m, 64);
    ww += __shfl_xor(ww, m, 64);
    xw += __shfl_xor(xw, m, 64);
  }
  if (lane == 0)
    coslab[r] = xw / (fmaxf(sqrtf(xx), 1e-12f) * fmaxf(sqrtf(ww), 1e-12f));
}

// One k-step with LITERAL ks (op_sel must be immediate). Operands are native
// i32x8 (no per-use construction). Refill writes the tuple's low half in place.
#define KS_STEP(KSL, ACC, ACCPREV, DOEXP_ODD, TT, CHNEXT)                     \
    ACC[0] = __builtin_amdgcn_mfma_scale_f32_16x16x128_f8f6f4(                \
        af8[0][KSL], b8[KSL], (KSL) == 0 ? fzero : ACC[0],                    \
        4, 4, KSL, asc0, KSL, bsc);                                           \
    ACC[1] = __builtin_amdgcn_mfma_scale_f32_16x16x128_f8f6f4(                \
        af8[1][KSL], b8[KSL], (KSL) == 0 ? fzero : ACC[1],                    \
        4, 4, KSL, asc1, KSL, bsc);                                           \
    if (DOEXP_ODD) {                                                          \
      _Pragma("unroll")                                                       \
      for (int r = 0; r < 4; ++r)                                             \
        accS[TT][r] += __uint_as_float(                                       \
            (unsigned)fmaf(ACCPREV[TT][r], 8388608.0f, FEC));                 \
    }                                                                         \
    *(i32x4*)&b8[KSL] =                                                       \
        *(const i32x4*)(gb + (size_t)(CHNEXT) * 4096 + (KSL) * 1024);

#define CHUNK_STEP(ACC, ACCPREV, DOEXP, CHNEXT)                               \
  {                                                                           \
    int nsc = *(const int*)(gsc + (size_t)(CHNEXT) * 256);                    \
    KS_STEP(0, ACC, ACCPREV, false, 0, CHNEXT)                                \
    KS_STEP(1, ACC, ACCPREV, DOEXP, 0, CHNEXT)                                \
    KS_STEP(2, ACC, ACCPREV, false, 0, CHNEXT)                                \
    KS_STEP(3, ACC, ACCPREV, DOEXP, 1, CHNEXT)                                \
    bsc = nsc;                                                                \
  }

// Fused MX-fp4 GEMM, barrier-free, 4 waves/SIMD, acc ping-pong.
__global__ __launch_bounds__(256, 4) void k_fused(
    const unsigned char* __restrict__ xn4, const unsigned char* __restrict__ xsc,
    const unsigned char* __restrict__ wt4, const unsigned char* __restrict__ wsc,
    float* __restrict__ pS) {
  const int tid = threadIdx.x;
  const int wv = tid >> 6, lane = tid & 63;
  const int g = lane >> 4, c = lane & 15;
  const int bid = blockIdx.x;
  const int logical = (bid & 7) * 128 + (bid >> 3);  // 1024 = 8*128 XCD swizzle
  const int sp = logical >> 6;          // 0..15 (2 splits per XCD)
  const int rb = logical & 63;          // 0..63
  const int row0 = rb * BM + wv * 32;   // this wave's 32 rows (2 tiles of 16)

  // 2 A-tiles fully K-resident, stored as native i32x8 (payload in low half).
  i32x8 af8[2][KS];
  int asc0, asc1;
  {
    const unsigned char* x0 = xn4 + (size_t)(row0 + c) * 256 + g * 16;
    const unsigned char* x1 = xn4 + (size_t)(row0 + 16 + c) * 256 + g * 16;
    #pragma unroll
    for (int ks = 0; ks < KS; ++ks) {
      i32x4 a0 = *(const i32x4*)(x0 + ks * 64);
      i32x4 a1 = *(const i32x4*)(x1 + ks * 64);
      af8[0][ks] = __builtin_shufflevector(a0, a0, 0, 1, 2, 3, -1, -1, -1, -1);
      af8[1][ks] = __builtin_shufflevector(a1, a1, 0, 1, 2, 3, -1, -1, -1, -1);
    }
    asc0 = *(const int*)(xsc + (size_t)(row0 + c) * 16 + g * 4);
    asc1 = *(const int*)(xsc + (size_t)(row0 + 16 + c) * 16 + g * 4);
  }

  float accS[2][4];
  #pragma unroll
  for (int t = 0; t < 2; ++t)
    #pragma unroll
    for (int r = 0; r < 4; ++r) accS[t][r] = 0.0f;

  const f32x4 fzero = (f32x4)0.0f;

  const unsigned char* gb = wt4 + (size_t)(sp * NCHUNK) * 4096 + lane * 16;
  const unsigned char* gsc = wsc + (size_t)(sp * NCHUNK) * 256 + c * 16 + g * 4;

  i32x8 b8[KS];
  #pragma unroll
  for (int ks = 0; ks < KS; ++ks) {
    i32x4 b0 = *(const i32x4*)(gb + ks * 1024);
    b8[ks] = __builtin_shufflevector(b0, b0, 0, 1, 2, 3, -1, -1, -1, -1);
  }
  int bsc = *(const int*)gsc;

  f32x4 accP[2], accQ[2];

  // Prologue: chunk 0 -> accP (no exps); prefetch chunk 1.
  CHUNK_STEP(accP, accQ, false, 1)

  for (int ch = 1; ch + 1 < NCHUNK; ch += 2) {
    CHUNK_STEP(accQ, accP, true, ch + 1)
    CHUNK_STEP(accP, accQ, true, (ch + 2 < NCHUNK ? ch + 2 : NCHUNK - 1))
  }
  // Tail: exps of accP (chunk 124).
  #pragma unroll
  for (int t = 0; t < 2; ++t)
    #pragma unroll
    for (int r = 0; r < 4; ++r)
      accS[t][r] += __uint_as_float((unsigned)fmaf(accP[t][r], 8388608.0f, FEC));

  // Sum over the 16 col-lanes of each group; write per-(row,split) partials.
  #pragma unroll
  for (int t = 0; t < 2; ++t)
    #pragma unroll
    for (int r = 0; r < 4; ++r) {
      float S = accS[t][r];
      #pragma unroll
      for (int m = 1; m <= 8; m <<= 1) S += __shfl_xor(S, m, 64);
      if (c == 0)
        pS[(size_t)sp * N + row0 + t * 16 + g * 4 + r] = S;
    }
}
#undef CHUNK_STEP
#undef KS_STEP

// Merge: S over splits (x e^-16); swap plain label term for f32 margin term; mean.
__global__ void k_merge(const float* __restrict__ pS, const float* __restrict__ coslab,
                        float* __restrict__ out) {
  int row = blockIdx.x * 256 + threadIdx.x;
  float S = 0.0f;
  #pragma unroll
  for (int s = 0; s < NSPLIT; ++s) S += pS[(size_t)s * N + row];
  float cl = coslab[row];
  float zp = SCL * cl;
  float ccl = fminf(fmaxf(cl, -1.0f + EPSC), 1.0f - EPSC);
  float zm = SCL * (ccl * COSM - sqrtf(1.0f - ccl * ccl) * SINM);
  float denom = S * EM16 - __expf(zp - SCL) + __expf(zm - SCL);
  float nll = SCL + logf(denom) - zm;
  #pragma unroll
  for (int m = 1; m <= 32; m <<= 1) nll += __shfl_xor(nll, m, 64);
  __shared__ float part[4];
  if ((threadIdx.x & 63) == 0) part[threadIdx.x >> 6] = nll;
  __syncthreads();
  if (threadIdx.x == 0)
    atomicAdd(out, (part[0] + part[1] + part[2] + part[3]) * (1.0f / N));
}

extern "C" void kernel_launch(void* const* d_in, const int* in_sizes, int n_in,
                              void* d_out, int out_size, void* d_ws, size_t ws_size,
                              hipStream_t stream) {
  const float* x = (const float*)d_in[0];
  const float* w = (const float*)d_in[1];
  const int* labels = (const int*)d_in[2];
  float* out = (float*)d_out;

  // ws: xn4 fp4 [N*256B] | xsc [N*16B] | wt4 fp4 [2000*4KB] | wsc [2000*256B]
  //   | pS f32 [NSPLIT*N] | coslab f32 [N]
  unsigned char* xn4 = (unsigned char*)d_ws;
  unsigned char* xsc = xn4 + (size_t)N * 256;
  unsigned char* wt4 = xsc + (size_t)N * 16;
  unsigned char* wsc = wt4 + (size_t)2000 * 4096;
  float* pS = (float*)(wsc + (size_t)2000 * 256);
  float* coslab = pS + (size_t)NSPLIT * N;

  hipLaunchKernelGGL(k_norm_x, dim3(N / 4), dim3(256), 0, stream,
                     x, (unsigned*)xn4, xsc, out);
  hipLaunchKernelGGL(k_normw_t, dim3(C / 16), dim3(256), 0, stream, w, wt4, wsc);
  hipLaunchKernelGGL(k_lab, dim3(N / 4), dim3(256), 0, stream, x, w, labels, coslab);
  hipLaunchKernelGGL(k_fused, dim3(64 * NSPLIT), dim3(256), 0, stream,
                     xn4, xsc, wt4, wsc, pS);
  hipLaunchKernelGGL(k_merge, dim3(N / 256), dim3(256), 0, stream, pS, coslab, out);
}

// Round 17
// 128.691 us; speedup vs baseline: 1.0769x; 1.0769x over previous
//
#include <hip/hip_runtime.h>

// ArcMarginLoss fused: normalize -> MX-fp4 MFMA GEMM + fixed-max softmax -> NLL mean.
// N=8192, D=512, C=32000, scale=16, margin=0.2.
// R17: R15 base (best, 108us: setprio + per-call up8) + dual register B-buffers
// with prefetch distance 2 (~1100cyc >> L2 ~225cyc; also kills the WAR of
// same-buffer refill). Tests the "all-waves stalled on B load at chunk head"
// hypothesis from R15/R16's both-pipes-<27% latency signature. ~110 VGPR,
// still 4 waves/SIMD.

typedef __attribute__((ext_vector_type(4))) float f32x4;
typedef __attribute__((ext_vector_type(4))) int i32x4;
typedef __attribute__((ext_vector_type(8))) int i32x8;

constexpr int N = 8192, D = 512, C = 32000;
constexpr int BM = 128;            // rows per block (4 waves x 2 tiles x 16 rows)
constexpr int NSPLIT = 16;         // column splits of C
constexpr int CPS = C / NSPLIT;    // 2000 cols per split
constexpr int NCHUNK = CPS / 16;   // 125 chunks of 16 cols
constexpr int KS = 4;              // 4 k-steps of K=128
constexpr float SCL = 16.0f;
constexpr float LOG2E = 1.4426950408889634f;
constexpr float S2 = SCL * LOG2E;              // folded into A pre-quant
constexpr float COSM = 0.98006657784124163f;  // cos(0.2)
constexpr float SINM = 0.19866933079506122f;  // sin(0.2)
constexpr float EPSC = 1e-7f;
constexpr float EM16 = 1.12535174719259114e-07f;  // exp(-16)
constexpr float FEC = 1064871712.0f;  // Schraudolph zero-mean magic (validated R12)

// fp4 e2m1 magnitude grid {0,.5,1,1.5,2,3,4,6} at codes 0..7.
__device__ __forceinline__ unsigned enc_fp4(float v, float inv) {
  unsigned s = (__float_as_uint(v) >> 31) << 3;
  float m = fabsf(v) * inv;
  float r = m < 2.0f ? 2.0f * m : (m < 4.0f ? m + 2.0f : fmaf(m, 0.5f, 4.0f));
  unsigned q = (unsigned)(r + 0.5f);
  return s | (q > 7u ? 7u : q);
}

// Per-32-block E8M0 scale from block absmax: smallest 2^e with absmax/2^e <= 6.
__device__ __forceinline__ void block_scale(float amax, unsigned& eB, float& inv) {
  unsigned u = __float_as_uint(amax * (1.0f / 6.0f));
  eB = (u >> 23) & 255u;
  if (u & 0x7fffffu) eB += 1u;      // ceil
  if (eB < 1u) eB = 1u;
  if (eB > 254u) eB = 254u;
  inv = __uint_as_float((254u - eB) << 23);  // 2^(127-eB)
}

__device__ __forceinline__ i32x8 up8(i32x4 v) {
  return __builtin_shufflevector(v, v, 0, 1, 2, 3, -1, -1, -1, -1);  // upper undef
}

// x: one wave per row. v = x_hat * S2; per-32-block scale; emit fp4 nibbles
// (row stride 256B) + scale bytes [row][g][ks] (16B/row). Zero-inits out scalar.
__global__ void k_norm_x(const float* __restrict__ in, unsigned* __restrict__ xn4,
                         unsigned char* __restrict__ xsc, float* __restrict__ outz) {
  if (blockIdx.x == 0 && threadIdx.x == 0) *outz = 0.0f;
  int w = (blockIdx.x << 2) + (threadIdx.x >> 6);
  int L = threadIdx.x & 63;
  const float* row = in + (size_t)w * D;
  float f[8];
  *(f32x4*)&f[0] = *(const f32x4*)(row + L * 8);
  *(f32x4*)&f[4] = *(const f32x4*)(row + L * 8 + 4);
  float ss = 0.f;
  #pragma unroll
  for (int i = 0; i < 8; ++i) ss += f[i] * f[i];
  #pragma unroll
  for (int m = 1; m <= 32; m <<= 1) ss += __shfl_xor(ss, m, 64);
  float sc = S2 / fmaxf(sqrtf(ss), 1e-12f);
  float v[8], am = 0.f;
  #pragma unroll
  for (int i = 0; i < 8; ++i) { v[i] = f[i] * sc; am = fmaxf(am, fabsf(v[i])); }
  am = fmaxf(am, __shfl_xor(am, 1, 64));
  am = fmaxf(am, __shfl_xor(am, 2, 64));   // quad (= one 32-elem block) absmax
  unsigned eB; float inv;
  block_scale(am, eB, inv);
  unsigned pk = 0;
  #pragma unroll
  for (int j = 0; j < 8; ++j) pk |= enc_fp4(v[j], inv) << (4 * j);
  xn4[(size_t)w * 64 + L] = pk;
  if ((L & 3) == 0) {
    int kb = L >> 2;  // block index; stored at [row][g=kb&3][ks=kb>>2]
    xsc[(size_t)w * 16 + (kb & 3) * 4 + (kb >> 2)] = (unsigned char)eB;
  }
}

// w: one block per 16-col group. Quantize to fp4 with per-32-block scales; emit
// chunk image (4KB, lane-contiguous for the fused per-lane 16B read) + 256B
// scale image [col][g][ks].
__global__ void k_normw_t(const float* __restrict__ in, unsigned char* __restrict__ wt4,
                          unsigned char* __restrict__ wsc) {
  __shared__ unsigned lbuf[1024];         // 4KB chunk image
  __shared__ unsigned char sbuf[256];     // scale image
  const int tid = threadIdx.x, wv = tid >> 6, L = tid & 63;
  const int gidx = blockIdx.x;
  #pragma unroll
  for (int t = 0; t < 4; ++t) {
    int rl = t * 4 + wv;  // 0..15 (col within group)
    const float* row = in + ((size_t)gidx * 16 + rl) * D;
    float f[8];
    *(f32x4*)&f[0] = *(const f32x4*)(row + L * 8);
    *(f32x4*)&f[4] = *(const f32x4*)(row + L * 8 + 4);
    float ss = 0.f;
    #pragma unroll
    for (int i = 0; i < 8; ++i) ss += f[i] * f[i];
    #pragma unroll
    for (int m = 1; m <= 32; m <<= 1) ss += __shfl_xor(ss, m, 64);
    float sc = 1.0f / fmaxf(sqrtf(ss), 1e-12f);
    float v[8], am = 0.f;
    #pragma unroll
    for (int i = 0; i < 8; ++i) { v[i] = f[i] * sc; am = fmaxf(am, fabsf(v[i])); }
    am = fmaxf(am, __shfl_xor(am, 1, 64));
    am = fmaxf(am, __shfl_xor(am, 2, 64));
    unsigned eB; float inv;
    block_scale(am, eB, inv);
    unsigned pk = 0;
    #pragma unroll
    for (int j = 0; j < 8; ++j) pk |= enc_fp4(v[j], inv) << (4 * j);
    // lane L covers k=8L..8L+8: ks=L>>4, g=(L>>2)&3, dword slot (L&3)
    lbuf[(L >> 4) * 256 + (((L >> 2) & 3) * 16 + rl) * 4 + (L & 3)] = pk;
    if ((L & 3) == 0)
      sbuf[rl * 16 + ((L >> 2) & 3) * 4 + (L >> 4)] = (unsigned char)eB;
  }
  __syncthreads();
  uint4* dst = (uint4*)(wt4 + (size_t)gidx * 4096);
  dst[tid] = ((const uint4*)lbuf)[tid];
  if (tid < 64)
    ((unsigned*)(wsc + (size_t)gidx * 256))[tid] = ((const unsigned*)sbuf)[tid];
}

// Label-column cosine in f32 (one wave per row) -> coslab[N].
__global__ void k_lab(const float* __restrict__ x, const float* __restrict__ w,
                      const int* __restrict__ labels, float* __restrict__ coslab) {
  int r = (blockIdx.x << 2) + (threadIdx.x >> 6);
  int lane = threadIdx.x & 63;
  const float* xr = x + (size_t)r * D;
  const float* wr = w + (size_t)labels[r] * D;
  f32x4 a = *(const f32x4*)(xr + lane * 8);
  f32x4 b = *(const f32x4*)(xr + lane * 8 + 4);
  f32x4 p = *(const f32x4*)(wr + lane * 8);
  f32x4 q = *(const f32x4*)(wr + lane * 8 + 4);
  float xx = a.x*a.x + a.y*a.y + a.z*a.z + a.w*a.w + b.x*b.x + b.y*b.y + b.z*b.z + b.w*b.w;
  float ww = p.x*p.x + p.y*p.y + p.z*p.z + p.w*p.w + q.x*q.x + q.y*q.y + q.z*q.z + q.w*q.w;
  float xw = a.x*p.x + a.y*p.y + a.z*p.z + a.w*p.w + b.x*q.x + b.y*q.y + b.z*q.z + b.w*q.w;
  #pragma unroll
  for (int m = 1; m <= 32; m <<= 1) {
    xx += __shfl_xor(xx, m, 64);
    ww += __shfl_xor(ww, m, 64);
    xw += __shfl_xor(xw, m, 64);
  }
  if (lane == 0)
    coslab[r] = xw / (fmaxf(sqrtf(xx), 1e-12f) * fmaxf(sqrtf(ww), 1e-12f));
}

// One k-step with LITERAL ks (op_sel must be immediate), against buffer BUF/BSC.
// ks=0 seeds fzero; DOEXP_ODD interleaves fast-exp2 of ACCPREV tile TT; then
// staggered refill of BUF[KSL] from chunk CHNEXT (2 ahead).
#define KS_STEP(KSL, ACC, ACCPREV, BUF, BSC, DOEXP_ODD, TT, CHNEXT)           \
    __builtin_amdgcn_s_setprio(1);                                            \
    ACC[0] = __builtin_amdgcn_mfma_scale_f32_16x16x128_f8f6f4(                \
        up8(af4[0][KSL]), up8(BUF[KSL]), (KSL) == 0 ? fzero : ACC[0],         \
        4, 4, KSL, asc0, KSL, BSC);                                           \
    ACC[1] = __builtin_amdgcn_mfma_scale_f32_16x16x128_f8f6f4(                \
        up8(af4[1][KSL]), up8(BUF[KSL]), (KSL) == 0 ? fzero : ACC[1],         \
        4, 4, KSL, asc1, KSL, BSC);                                           \
    __builtin_amdgcn_s_setprio(0);                                            \
    if (DOEXP_ODD) {                                                          \
      _Pragma("unroll")                                                       \
      for (int r = 0; r < 4; ++r)                                             \
        accS[TT][r] += __uint_as_float(                                       \
            (unsigned)fmaf(ACCPREV[TT][r], 8388608.0f, FEC));                 \
    }                                                                         \
    BUF[KSL] = *(const i32x4*)(gb + (size_t)(CHNEXT) * 4096 + (KSL) * 1024);

#define CHUNK_STEP(ACC, ACCPREV, BUF, BSC, DOEXP, CHNEXT)                     \
  {                                                                           \
    int nsc = *(const int*)(gsc + (size_t)(CHNEXT) * 256);                    \
    KS_STEP(0, ACC, ACCPREV, BUF, BSC, false, 0, CHNEXT)                      \
    KS_STEP(1, ACC, ACCPREV, BUF, BSC, DOEXP, 0, CHNEXT)                      \
    KS_STEP(2, ACC, ACCPREV, BUF, BSC, false, 0, CHNEXT)                      \
    KS_STEP(3, ACC, ACCPREV, BUF, BSC, DOEXP, 1, CHNEXT)                      \
    BSC = nsc;                                                                \
  }

// Fused MX-fp4 GEMM, barrier-free, 4 waves/SIMD, acc ping-pong, depth-2 prefetch.
__global__ __launch_bounds__(256, 4) void k_fused(
    const unsigned char* __restrict__ xn4, const unsigned char* __restrict__ xsc,
    const unsigned char* __restrict__ wt4, const unsigned char* __restrict__ wsc,
    float* __restrict__ pS) {
  const int tid = threadIdx.x;
  const int wv = tid >> 6, lane = tid & 63;
  const int g = lane >> 4, c = lane & 15;
  const int bid = blockIdx.x;
  const int logical = (bid & 7) * 128 + (bid >> 3);  // 1024 = 8*128 XCD swizzle
  const int sp = logical >> 6;          // 0..15 (2 splits per XCD)
  const int rb = logical & 63;          // 0..63
  const int row0 = rb * BM + wv * 32;   // this wave's 32 rows (2 tiles of 16)

  // 2 A-tiles fully K-resident as fp4: af4[t][ks] = 16B at row*256 + ks*64 + g*16.
  i32x4 af4[2][KS];
  int asc0, asc1;
  {
    const unsigned char* x0 = xn4 + (size_t)(row0 + c) * 256 + g * 16;
    const unsigned char* x1 = xn4 + (size_t)(row0 + 16 + c) * 256 + g * 16;
    #pragma unroll
    for (int ks = 0; ks < KS; ++ks) {
      af4[0][ks] = *(const i32x4*)(x0 + ks * 64);
      af4[1][ks] = *(const i32x4*)(x1 + ks * 64);
    }
    asc0 = *(const int*)(xsc + (size_t)(row0 + c) * 16 + g * 4);
    asc1 = *(const int*)(xsc + (size_t)(row0 + 16 + c) * 16 + g * 4);
  }

  float accS[2][4];
  #pragma unroll
  for (int t = 0; t < 2; ++t)
    #pragma unroll
    for (int r = 0; r < 4; ++r) accS[t][r] = 0.0f;

  const f32x4 fzero = (f32x4)0.0f;

  const unsigned char* gb = wt4 + (size_t)(sp * NCHUNK) * 4096 + lane * 16;
  const unsigned char* gsc = wsc + (size_t)(sp * NCHUNK) * 256 + c * 16 + g * 4;

  // Dual B buffers: b4A holds even chunks, b4B odd chunks; each refilled 2 ahead.
  i32x4 b4A[KS], b4B[KS];
  #pragma unroll
  for (int ks = 0; ks < KS; ++ks) {
    b4A[ks] = *(const i32x4*)(gb + ks * 1024);
    b4B[ks] = *(const i32x4*)(gb + 4096 + ks * 1024);
  }
  int bscA = *(const int*)gsc;
  int bscB = *(const int*)(gsc + 256);

  f32x4 accP[2], accQ[2];

  // Prologue: chunk 0 (accP, no exps), refill A<-2; chunk 1 (accQ, exps of 0),
  // refill B<-3.
  CHUNK_STEP(accP, accQ, b4A, bscA, false, 2)
  CHUNK_STEP(accQ, accP, b4B, bscB, true, 3)

  for (int ch = 2; ch + 1 < NCHUNK; ch += 2) {
    // even chunk ch from A -> accP, exps of accQ (ch-1); refill A <- ch+2.
    CHUNK_STEP(accP, accQ, b4A, bscA, true, ch + 2)
    // odd chunk ch+1 from B -> accQ, exps of accP (ch); refill B <- ch+3 (clamp).
    CHUNK_STEP(accQ, accP, b4B, bscB, true, (ch + 3 < NCHUNK ? ch + 3 : NCHUNK - 1))
  }
  // Final even chunk 124 from A (refilled during ch=122), exps of accQ (123).
  CHUNK_STEP(accP, accQ, b4A, bscA, true, NCHUNK - 1)
  // Tail: exps of accP (chunk 124).
  #pragma unroll
  for (int t = 0; t < 2; ++t)
    #pragma unroll
    for (int r = 0; r < 4; ++r)
      accS[t][r] += __uint_as_float((unsigned)fmaf(accP[t][r], 8388608.0f, FEC));

  // Sum over the 16 col-lanes of each group; write per-(row,split) partials.
  #pragma unroll
  for (int t = 0; t < 2; ++t)
    #pragma unroll
    for (int r = 0; r < 4; ++r) {
      float S = accS[t][r];
      #pragma unroll
      for (int m = 1; m <= 8; m <<= 1) S += __shfl_xor(S, m, 64);
      if (c == 0)
        pS[(size_t)sp * N + row0 + t * 16 + g * 4 + r] = S;
    }
}
#undef CHUNK_STEP
#undef KS_STEP

// Merge: S over splits (x e^-16); swap plain label term for f32 margin term; mean.
__global__ void k_merge(const float* __restrict__ pS, const float* __restrict__ coslab,
                        float* __restrict__ out) {
  int row = blockIdx.x * 256 + threadIdx.x;
  float S = 0.0f;
  #pragma unroll
  for (int s = 0; s < NSPLIT; ++s) S += pS[(size_t)s * N + row];
  float cl = coslab[row];
  float zp = SCL * cl;
  float ccl = fminf(fmaxf(cl, -1.0f + EPSC), 1.0f - EPSC);
  float zm = SCL * (ccl * COSM - sqrtf(1.0f - ccl * ccl) * SINM);
  float denom = S * EM16 - __expf(zp - SCL) + __expf(zm - SCL);
  float nll = SCL + logf(denom) - zm;
  #pragma unroll
  for (int m = 1; m <= 32; m <<= 1) nll += __shfl_xor(nll, m, 64);
  __shared__ float part[4];
  if ((threadIdx.x & 63) == 0) part[threadIdx.x >> 6] = nll;
  __syncthreads();
  if (threadIdx.x == 0)
    atomicAdd(out, (part[0] + part[1] + part[2] + part[3]) * (1.0f / N));
}

extern "C" void kernel_launch(void* const* d_in, const int* in_sizes, int n_in,
                              void* d_out, int out_size, void* d_ws, size_t ws_size,
                              hipStream_t stream) {
  const float* x = (const float*)d_in[0];
  const float* w = (const float*)d_in[1];
  const int* labels = (const int*)d_in[2];
  float* out = (float*)d_out;

  // ws: xn4 fp4 [N*256B] | xsc [N*16B] | wt4 fp4 [2000*4KB] | wsc [2000*256B]
  //   | pS f32 [NSPLIT*N] | coslab f32 [N]
  unsigned char* xn4 = (unsigned char*)d_ws;
  unsigned char* xsc = xn4 + (size_t)N * 256;
  unsigned char* wt4 = xsc + (size_t)N * 16;
  unsigned char* wsc = wt4 + (size_t)2000 * 4096;
  float* pS = (float*)(wsc + (size_t)2000 * 256);
  float* coslab = pS + (size_t)NSPLIT * N;

  hipLaunchKernelGGL(k_norm_x, dim3(N / 4), dim3(256), 0, stream,
                     x, (unsigned*)xn4, xsc, out);
  hipLaunchKernelGGL(k_normw_t, dim3(C / 16), dim3(256), 0, stream, w, wt4, wsc);
  hipLaunchKernelGGL(k_lab, dim3(N / 4), dim3(256), 0, stream, x, w, labels, coslab);
  hipLaunchKernelGGL(k_fused, dim3(64 * NSPLIT), dim3(256), 0, stream,
                     xn4, xsc, wt4, wsc, pS);
  hipLaunchKernelGGL(k_merge, dim3(N / 256), dim3(256), 0, stream, pS, coslab, out);
}

// Round 18
// 125.517 us; speedup vs baseline: 1.1041x; 1.0253x over previous
//
#include <hip/hip_runtime.h>

// ArcMarginLoss fused: normalize -> MX-fp4 MFMA GEMM + fixed-max softmax -> NLL mean.
// N=8192, D=512, C=32000, scale=16, margin=0.2.
// R18: single-variable test vs R15 (108us best): SPLIT-K accumulator chains.
// Each tile's 4-deep serial MFMA chain (ks0..3) becomes two 2-deep independent
// chains (E: ks0,ks1 / O: ks2,ks3), merged with one add before the fast-exp
// (z = zE + zO, exact). Doubles independent chains per SIMD (6 -> 12) to cover
// MFMA dependent latency — the surviving hypothesis after depth-2 prefetch (R17)
// and VALU cuts (R11/R12) came back null. All else identical to R15.

typedef __attribute__((ext_vector_type(4))) float f32x4;
typedef __attribute__((ext_vector_type(4))) int i32x4;
typedef __attribute__((ext_vector_type(8))) int i32x8;

constexpr int N = 8192, D = 512, C = 32000;
constexpr int BM = 128;            // rows per block (4 waves x 2 tiles x 16 rows)
constexpr int NSPLIT = 16;         // column splits of C
constexpr int CPS = C / NSPLIT;    // 2000 cols per split
constexpr int NCHUNK = CPS / 16;   // 125 chunks of 16 cols
constexpr int KS = 4;              // 4 k-steps of K=128
constexpr float SCL = 16.0f;
constexpr float LOG2E = 1.4426950408889634f;
constexpr float S2 = SCL * LOG2E;              // folded into A pre-quant
constexpr float COSM = 0.98006657784124163f;  // cos(0.2)
constexpr float SINM = 0.19866933079506122f;  // sin(0.2)
constexpr float EPSC = 1e-7f;
constexpr float EM16 = 1.12535174719259114e-07f;  // exp(-16)
constexpr float FEC = 1064871712.0f;  // Schraudolph zero-mean magic (validated R12)

// fp4 e2m1 magnitude grid {0,.5,1,1.5,2,3,4,6} at codes 0..7.
__device__ __forceinline__ unsigned enc_fp4(float v, float inv) {
  unsigned s = (__float_as_uint(v) >> 31) << 3;
  float m = fabsf(v) * inv;
  float r = m < 2.0f ? 2.0f * m : (m < 4.0f ? m + 2.0f : fmaf(m, 0.5f, 4.0f));
  unsigned q = (unsigned)(r + 0.5f);
  return s | (q > 7u ? 7u : q);
}

// Per-32-block E8M0 scale from block absmax: smallest 2^e with absmax/2^e <= 6.
__device__ __forceinline__ void block_scale(float amax, unsigned& eB, float& inv) {
  unsigned u = __float_as_uint(amax * (1.0f / 6.0f));
  eB = (u >> 23) & 255u;
  if (u & 0x7fffffu) eB += 1u;      // ceil
  if (eB < 1u) eB = 1u;
  if (eB > 254u) eB = 254u;
  inv = __uint_as_float((254u - eB) << 23);  // 2^(127-eB)
}

__device__ __forceinline__ i32x8 up8(i32x4 v) {
  return __builtin_shufflevector(v, v, 0, 1, 2, 3, -1, -1, -1, -1);  // upper undef
}

// x: one wave per row. v = x_hat * S2; per-32-block scale; emit fp4 nibbles
// (row stride 256B) + scale bytes [row][g][ks] (16B/row). Zero-inits out scalar.
__global__ void k_norm_x(const float* __restrict__ in, unsigned* __restrict__ xn4,
                         unsigned char* __restrict__ xsc, float* __restrict__ outz) {
  if (blockIdx.x == 0 && threadIdx.x == 0) *outz = 0.0f;
  int w = (blockIdx.x << 2) + (threadIdx.x >> 6);
  int L = threadIdx.x & 63;
  const float* row = in + (size_t)w * D;
  float f[8];
  *(f32x4*)&f[0] = *(const f32x4*)(row + L * 8);
  *(f32x4*)&f[4] = *(const f32x4*)(row + L * 8 + 4);
  float ss = 0.f;
  #pragma unroll
  for (int i = 0; i < 8; ++i) ss += f[i] * f[i];
  #pragma unroll
  for (int m = 1; m <= 32; m <<= 1) ss += __shfl_xor(ss, m, 64);
  float sc = S2 / fmaxf(sqrtf(ss), 1e-12f);
  float v[8], am = 0.f;
  #pragma unroll
  for (int i = 0; i < 8; ++i) { v[i] = f[i] * sc; am = fmaxf(am, fabsf(v[i])); }
  am = fmaxf(am, __shfl_xor(am, 1, 64));
  am = fmaxf(am, __shfl_xor(am, 2, 64));   // quad (= one 32-elem block) absmax
  unsigned eB; float inv;
  block_scale(am, eB, inv);
  unsigned pk = 0;
  #pragma unroll
  for (int j = 0; j < 8; ++j) pk |= enc_fp4(v[j], inv) << (4 * j);
  xn4[(size_t)w * 64 + L] = pk;
  if ((L & 3) == 0) {
    int kb = L >> 2;  // block index; stored at [row][g=kb&3][ks=kb>>2]
    xsc[(size_t)w * 16 + (kb & 3) * 4 + (kb >> 2)] = (unsigned char)eB;
  }
}

// w: one block per 16-col group. Quantize to fp4 with per-32-block scales; emit
// chunk image (4KB, lane-contiguous for the fused per-lane 16B read) + 256B
// scale image [col][g][ks].
__global__ void k_normw_t(const float* __restrict__ in, unsigned char* __restrict__ wt4,
                          unsigned char* __restrict__ wsc) {
  __shared__ unsigned lbuf[1024];         // 4KB chunk image
  __shared__ unsigned char sbuf[256];     // scale image
  const int tid = threadIdx.x, wv = tid >> 6, L = tid & 63;
  const int gidx = blockIdx.x;
  #pragma unroll
  for (int t = 0; t < 4; ++t) {
    int rl = t * 4 + wv;  // 0..15 (col within group)
    const float* row = in + ((size_t)gidx * 16 + rl) * D;
    float f[8];
    *(f32x4*)&f[0] = *(const f32x4*)(row + L * 8);
    *(f32x4*)&f[4] = *(const f32x4*)(row + L * 8 + 4);
    float ss = 0.f;
    #pragma unroll
    for (int i = 0; i < 8; ++i) ss += f[i] * f[i];
    #pragma unroll
    for (int m = 1; m <= 32; m <<= 1) ss += __shfl_xor(ss, m, 64);
    float sc = 1.0f / fmaxf(sqrtf(ss), 1e-12f);
    float v[8], am = 0.f;
    #pragma unroll
    for (int i = 0; i < 8; ++i) { v[i] = f[i] * sc; am = fmaxf(am, fabsf(v[i])); }
    am = fmaxf(am, __shfl_xor(am, 1, 64));
    am = fmaxf(am, __shfl_xor(am, 2, 64));
    unsigned eB; float inv;
    block_scale(am, eB, inv);
    unsigned pk = 0;
    #pragma unroll
    for (int j = 0; j < 8; ++j) pk |= enc_fp4(v[j], inv) << (4 * j);
    // lane L covers k=8L..8L+8: ks=L>>4, g=(L>>2)&3, dword slot (L&3)
    lbuf[(L >> 4) * 256 + (((L >> 2) & 3) * 16 + rl) * 4 + (L & 3)] = pk;
    if ((L & 3) == 0)
      sbuf[rl * 16 + ((L >> 2) & 3) * 4 + (L >> 4)] = (unsigned char)eB;
  }
  __syncthreads();
  uint4* dst = (uint4*)(wt4 + (size_t)gidx * 4096);
  dst[tid] = ((const uint4*)lbuf)[tid];
  if (tid < 64)
    ((unsigned*)(wsc + (size_t)gidx * 256))[tid] = ((const unsigned*)sbuf)[tid];
}

// Label-column cosine in f32 (one wave per row) -> coslab[N].
__global__ void k_lab(const float* __restrict__ x, const float* __restrict__ w,
                      const int* __restrict__ labels, float* __restrict__ coslab) {
  int r = (blockIdx.x << 2) + (threadIdx.x >> 6);
  int lane = threadIdx.x & 63;
  const float* xr = x + (size_t)r * D;
  const float* wr = w + (size_t)labels[r] * D;
  f32x4 a = *(const f32x4*)(xr + lane * 8);
  f32x4 b = *(const f32x4*)(xr + lane * 8 + 4);
  f32x4 p = *(const f32x4*)(wr + lane * 8);
  f32x4 q = *(const f32x4*)(wr + lane * 8 + 4);
  float xx = a.x*a.x + a.y*a.y + a.z*a.z + a.w*a.w + b.x*b.x + b.y*b.y + b.z*b.z + b.w*b.w;
  float ww = p.x*p.x + p.y*p.y + p.z*p.z + p.w*p.w + q.x*q.x + q.y*q.y + q.z*q.z + q.w*q.w;
  float xw = a.x*p.x + a.y*p.y + a.z*p.z + a.w*p.w + b.x*q.x + b.y*q.y + b.z*q.z + b.w*q.w;
  #pragma unroll
  for (int m = 1; m <= 32; m <<= 1) {
    xx += __shfl_xor(xx, m, 64);
    ww += __shfl_xor(ww, m, 64);
    xw += __shfl_xor(xw, m, 64);
  }
  if (lane == 0)
    coslab[r] = xw / (fmaxf(sqrtf(xx), 1e-12f) * fmaxf(sqrtf(ww), 1e-12f));
}

// One k-step with LITERAL ks (op_sel must be immediate). SEED==true seeds the
// chain from fzero (chain heads: ks0 for E, ks2 for O). DOEXP interleaves the
// fast-exp2 of the PREVIOUS chunk's merged chains for tile TT. Staggered refill.
#define KS_STEP(KSL, ACC, SEED, DOEXP, PE, PO, TT, CHNEXT)                    \
    __builtin_amdgcn_s_setprio(1);                                            \
    ACC[0] = __builtin_amdgcn_mfma_scale_f32_16x16x128_f8f6f4(                \
        up8(af4[0][KSL]), up8(b4[KSL]), (SEED) ? fzero : ACC[0],              \
        4, 4, KSL, asc0, KSL, bsc);                                           \
    ACC[1] = __builtin_amdgcn_mfma_scale_f32_16x16x128_f8f6f4(                \
        up8(af4[1][KSL]), up8(b4[KSL]), (SEED) ? fzero : ACC[1],              \
        4, 4, KSL, asc1, KSL, bsc);                                           \
    __builtin_amdgcn_s_setprio(0);                                            \
    if (DOEXP) {                                                              \
      _Pragma("unroll")                                                       \
      for (int r = 0; r < 4; ++r)                                             \
        accS[TT][r] += __uint_as_float(                                       \
            (unsigned)fmaf(PE[TT][r] + PO[TT][r], 8388608.0f, FEC));          \
    }                                                                         \
    b4[KSL] = *(const i32x4*)(gb + (size_t)(CHNEXT) * 4096 + (KSL) * 1024);

// One chunk into chains (AE: ks0,ks1 | AO: ks2,ks3); exps of prev chunk's
// merged chains (PE+PO) interleaved at ks1 (tile 0) and ks3 (tile 1).
#define CHUNK_STEP(AE, AO, PE, PO, DOEXP, CHNEXT)                             \
  {                                                                           \
    int nsc = *(const int*)(gsc + (size_t)(CHNEXT) * 256);                    \
    KS_STEP(0, AE, true,  false, PE, PO, 0, CHNEXT)                           \
    KS_STEP(1, AE, false, DOEXP, PE, PO, 0, CHNEXT)                           \
    KS_STEP(2, AO, true,  false, PE, PO, 0, CHNEXT)                           \
    KS_STEP(3, AO, false, DOEXP, PE, PO, 1, CHNEXT)                           \
    bsc = nsc;                                                                \
  }

// Fused MX-fp4 GEMM, barrier-free, acc ping-pong with split-K chains.
__global__ __launch_bounds__(256, 4) void k_fused(
    const unsigned char* __restrict__ xn4, const unsigned char* __restrict__ xsc,
    const unsigned char* __restrict__ wt4, const unsigned char* __restrict__ wsc,
    float* __restrict__ pS) {
  const int tid = threadIdx.x;
  const int wv = tid >> 6, lane = tid & 63;
  const int g = lane >> 4, c = lane & 15;
  const int bid = blockIdx.x;
  const int logical = (bid & 7) * 128 + (bid >> 3);  // 1024 = 8*128 XCD swizzle
  const int sp = logical >> 6;          // 0..15 (2 splits per XCD)
  const int rb = logical & 63;          // 0..63
  const int row0 = rb * BM + wv * 32;   // this wave's 32 rows (2 tiles of 16)

  // 2 A-tiles fully K-resident as fp4: af4[t][ks] = 16B at row*256 + ks*64 + g*16.
  i32x4 af4[2][KS];
  int asc0, asc1;
  {
    const unsigned char* x0 = xn4 + (size_t)(row0 + c) * 256 + g * 16;
    const unsigned char* x1 = xn4 + (size_t)(row0 + 16 + c) * 256 + g * 16;
    #pragma unroll
    for (int ks = 0; ks < KS; ++ks) {
      af4[0][ks] = *(const i32x4*)(x0 + ks * 64);
      af4[1][ks] = *(const i32x4*)(x1 + ks * 64);
    }
    asc0 = *(const int*)(xsc + (size_t)(row0 + c) * 16 + g * 4);
    asc1 = *(const int*)(xsc + (size_t)(row0 + 16 + c) * 16 + g * 4);
  }

  float accS[2][4];
  #pragma unroll
  for (int t = 0; t < 2; ++t)
    #pragma unroll
    for (int r = 0; r < 4; ++r) accS[t][r] = 0.0f;

  const f32x4 fzero = (f32x4)0.0f;

  const unsigned char* gb = wt4 + (size_t)(sp * NCHUNK) * 4096 + lane * 16;
  const unsigned char* gsc = wsc + (size_t)(sp * NCHUNK) * 256 + c * 16 + g * 4;

  i32x4 b4[KS];
  #pragma unroll
  for (int ks = 0; ks < KS; ++ks) b4[ks] = *(const i32x4*)(gb + ks * 1024);
  int bsc = *(const int*)gsc;

  // Ping-pong sets, each with independent E/O chains (depth 2 each).
  f32x4 accPE[2], accPO[2], accQE[2], accQO[2];

  // Prologue: chunk 0 -> P chains (no exps); prefetch chunk 1.
  CHUNK_STEP(accPE, accPO, accQE, accQO, false, 1)

  for (int ch = 1; ch + 1 < NCHUNK; ch += 2) {
    CHUNK_STEP(accQE, accQO, accPE, accPO, true, ch + 1)
    CHUNK_STEP(accPE, accPO, accQE, accQO, true,
               (ch + 2 < NCHUNK ? ch + 2 : NCHUNK - 1))
  }
  // Tail: exps of P (chunk 124), merged chains.
  #pragma unroll
  for (int t = 0; t < 2; ++t)
    #pragma unroll
    for (int r = 0; r < 4; ++r)
      accS[t][r] += __uint_as_float(
          (unsigned)fmaf(accPE[t][r] + accPO[t][r], 8388608.0f, FEC));

  // Sum over the 16 col-lanes of each group; write per-(row,split) partials.
  #pragma unroll
  for (int t = 0; t < 2; ++t)
    #pragma unroll
    for (int r = 0; r < 4; ++r) {
      float S = accS[t][r];
      #pragma unroll
      for (int m = 1; m <= 8; m <<= 1) S += __shfl_xor(S, m, 64);
      if (c == 0)
        pS[(size_t)sp * N + row0 + t * 16 + g * 4 + r] = S;
    }
}
#undef CHUNK_STEP
#undef KS_STEP

// Merge: S over splits (x e^-16); swap plain label term for f32 margin term; mean.
__global__ void k_merge(const float* __restrict__ pS, const float* __restrict__ coslab,
                        float* __restrict__ out) {
  int row = blockIdx.x * 256 + threadIdx.x;
  float S = 0.0f;
  #pragma unroll
  for (int s = 0; s < NSPLIT; ++s) S += pS[(size_t)s * N + row];
  float cl = coslab[row];
  float zp = SCL * cl;
  float ccl = fminf(fmaxf(cl, -1.0f + EPSC), 1.0f - EPSC);
  float zm = SCL * (ccl * COSM - sqrtf(1.0f - ccl * ccl) * SINM);
  float denom = S * EM16 - __expf(zp - SCL) + __expf(zm - SCL);
  float nll = SCL + logf(denom) - zm;
  #pragma unroll
  for (int m = 1; m <= 32; m <<= 1) nll += __shfl_xor(nll, m, 64);
  __shared__ float part[4];
  if ((threadIdx.x & 63) == 0) part[threadIdx.x >> 6] = nll;
  __syncthreads();
  if (threadIdx.x == 0)
    atomicAdd(out, (part[0] + part[1] + part[2] + part[3]) * (1.0f / N));
}

extern "C" void kernel_launch(void* const* d_in, const int* in_sizes, int n_in,
                              void* d_out, int out_size, void* d_ws, size_t ws_size,
                              hipStream_t stream) {
  const float* x = (const float*)d_in[0];
  const float* w = (const float*)d_in[1];
  const int* labels = (const int*)d_in[2];
  float* out = (float*)d_out;

  // ws: xn4 fp4 [N*256B] | xsc [N*16B] | wt4 fp4 [2000*4KB] | wsc [2000*256B]
  //   | pS f32 [NSPLIT*N] | coslab f32 [N]
  unsigned char* xn4 = (unsigned char*)d_ws;
  unsigned char* xsc = xn4 + (size_t)N * 256;
  unsigned char* wt4 = xsc + (size_t)N * 16;
  unsigned char* wsc = wt4 + (size_t)2000 * 4096;
  float* pS = (float*)(wsc + (size_t)2000 * 256);
  float* coslab = pS + (size_t)NSPLIT * N;

  hipLaunchKernelGGL(k_norm_x, dim3(N / 4), dim3(256), 0, stream,
                     x, (unsigned*)xn4, xsc, out);
  hipLaunchKernelGGL(k_normw_t, dim3(C / 16), dim3(256), 0, stream, w, wt4, wsc);
  hipLaunchKernelGGL(k_lab, dim3(N / 4), dim3(256), 0, stream, x, w, labels, coslab);
  hipLaunchKernelGGL(k_fused, dim3(64 * NSPLIT), dim3(256), 0, stream,
                     xn4, xsc, wt4, wsc, pS);
  hipLaunchKernelGGL(k_merge, dim3(N / 256), dim3(256), 0, stream, pS, coslab, out);
}